// Round 1
// baseline (709.393 us; speedup 1.0000x reference)
//
#include <hip/hip_runtime.h>

// Linear-chain CRF log-partition (backward DP) for B=64, S=1024, T=128.
//
// Design: one workgroup (256 thr = 4 waves) per batch chain; 1023 sequential
// steps. E = exp(transitions) lives entirely in VGPRs (thread t holds row
// i = t&127, j-half h = t>>7 : 64 floats). Per step:
//   p[j]   = exp(em[n+1,j] + B[j] - d)       (threads 0..127, "owners")
//   s[i]   = sum_j E[i,j] * p[j]             (matvec, all 256 threads)
//   B[i]   = log(s[i]);  O += d              (shift bookkeeping)
// d is t_0 from two active steps ago (broadcast via 1 LDS word) -- bounded
// exponents without any per-step max reduction. logZ = O + lse(final).

#define B_  64
#define S_  1024
#define T_  128
#define PAD_IDX 0
#define EOS_IDX 3
#define BOT_IDX 1

__global__ __launch_bounds__(256) void crf_logz_kernel(
    const int*   __restrict__ W,
    const float* __restrict__ emissions,
    const float* __restrict__ transitions,
    float*       __restrict__ out)
{
  const int b = blockIdx.x;
  const int t = threadIdx.x;
  const int i = t & 127;          // tag row owned for the matvec
  const int h = t >> 7;           // j-half: 0 -> j in [0,64), 1 -> [64,128)
  const bool owner = (h == 0);    // threads 0..127 own Beta[i]

  __shared__ __align__(16) float pbuf[T_];   // p values (broadcast-read as float4)
  __shared__ float part[T_];                 // partial sums from h=1 half
  __shared__ float tbuf;                     // t_0 broadcast (shift chain)

  // ---- Precompute E = exp(transitions) into registers: row i, cols h*64+[0,64)
  float4 Ereg[16];
  {
    const float4* tr4 = (const float4*)transitions + i * (T_ / 4) + h * 16;
    #pragma unroll
    for (int k = 0; k < 16; ++k) {
      float4 v = tr4[k];
      Ereg[k].x = __expf(v.x);
      Ereg[k].y = __expf(v.y);
      Ereg[k].z = __expf(v.z);
      Ereg[k].w = __expf(v.w);
    }
  }

  const int*   Wrow = W + b * S_;
  const float* emb  = emissions + (size_t)b * S_ * T_;

  float Breg = 0.0f;   // owner: B[i] (shifted Beta)
  float d    = 0.0f;   // current normalization shift
  float O    = 0.0f;   // accumulated offset (sum of shifts used)
  if (t == 0) tbuf = 0.0f;
  __syncthreads();

  // prefetch for n = S_-2 : consumes W[b,S_-1], em[b,S_-1,i]
  int   w_cur  = Wrow[S_ - 1];
  float em_cur = owner ? emb[(size_t)(S_ - 1) * T_ + i] : 0.0f;

  for (int n = S_ - 2; n >= 0; --n) {
    // prefetch next iteration's inputs (em[b,n,i] is em0 when n==0)
    int   w_nxt  = Wrow[n];
    float em_nxt = owner ? emb[(size_t)n * T_ + i] : 0.0f;

    bool active = (w_cur != PAD_IDX) & (w_cur != EOS_IDX);   // wave-uniform
    if (active) {
      if (owner) {
        float p = __expf(em_cur + Breg - d);
        pbuf[i] = p;
      }
      __syncthreads();                       // barrier 1: pbuf visible
      float d_next = tbuf;                   // t_0 written at end of prev active step

      // matvec half: acc = sum_{k in half h} E[i,k] * p[k]
      float4 acc4 = {0.f, 0.f, 0.f, 0.f};
      const float4* pb4 = (const float4*)pbuf + h * 16;
      #pragma unroll
      for (int k = 0; k < 16; ++k) {
        float4 p4 = pb4[k];                  // broadcast ds_read_b128
        acc4.x = fmaf(Ereg[k].x, p4.x, acc4.x);
        acc4.y = fmaf(Ereg[k].y, p4.y, acc4.y);
        acc4.z = fmaf(Ereg[k].z, p4.z, acc4.z);
        acc4.w = fmaf(Ereg[k].w, p4.w, acc4.w);
      }
      float acc = (acc4.x + acc4.y) + (acc4.z + acc4.w);
      if (!owner) part[i] = acc;
      __syncthreads();                       // barrier 2: partials visible
      if (owner) {
        float s  = acc + part[i];
        float tt = __logf(s);
        Breg = tt;
        O += d;
        if (i == 0) tbuf = tt;               // becomes d two steps later
      }
      d = d_next;
    }
    w_cur  = w_nxt;
    em_cur = em_nxt;
  }

  // final: f[i] = trans[BOT,i] + em[b,0,i] + B[i];  logZ = O + logsumexp(f)
  if (owner) {
    float f = transitions[BOT_IDX * T_ + i] + em_cur + Breg;
    pbuf[i] = f;
  }
  __syncthreads();
  if (t == 0) {
    float m = -3.4e38f;
    #pragma unroll 4
    for (int k = 0; k < T_; ++k) m = fmaxf(m, pbuf[k]);
    float s = 0.f;
    #pragma unroll 4
    for (int k = 0; k < T_; ++k) s += __expf(pbuf[k] - m);
    out[b] = O + m + __logf(s);
  }
}

extern "C" void kernel_launch(void* const* d_in, const int* in_sizes, int n_in,
                              void* d_out, int out_size, void* d_ws, size_t ws_size,
                              hipStream_t stream) {
  const int*   W     = (const int*)d_in[0];
  const float* em    = (const float*)d_in[1];
  const float* trans = (const float*)d_in[2];
  float*       out   = (float*)d_out;
  (void)in_sizes; (void)n_in; (void)out_size; (void)d_ws; (void)ws_size;
  crf_logz_kernel<<<B_, 256, 0, stream>>>(W, em, trans, out);
}